// Round 2
// baseline (1515.657 us; speedup 1.0000x reference)
//
#include <hip/hip_runtime.h>
#include <hip/hip_bf16.h>

#define VOCAB 32000
#define DIM 1024
#define NTOK 4096
#define NG 5
#define MAXTILES 255

typedef float f32x4 __attribute__((ext_vector_type(4)));
typedef __bf16 bf16x8 __attribute__((ext_vector_type(8)));

__device__ __forceinline__ unsigned short f2bf(float f) {
    union { float f; unsigned int u; } x; x.f = f;
    unsigned int r = x.u + 0x7fffu + ((x.u >> 16) & 1u);
    return (unsigned short)(r >> 16);
}

__device__ __forceinline__ void gload16(const void* g, void* l) {
    __builtin_amdgcn_global_load_lds(
        (const __attribute__((address_space(1))) void*)g,
        (__attribute__((address_space(3))) void*)l, 16, 0, 0);
}

// ---------------- selector scan: stable bucket columns by selector ----------
__global__ __launch_bounds__(1024) void scan_kernel(const float* __restrict__ gates_w,
                                                    int* __restrict__ pos,
                                                    int* __restrict__ jlist,
                                                    int4* __restrict__ tdesc) {
    __shared__ int cnt[NG], pbase[NG], runbase[NG];
    __shared__ int wtot[16][NG], wpre[16][NG], ctot[NG];
    const int tid = threadIdx.x;
    const int lane = tid & 63, wv = tid >> 6;
    if (tid < NG) { cnt[tid] = 0; runbase[tid] = 0; }
    __syncthreads();
    int loc[NG] = {0, 0, 0, 0, 0};
    for (int i = tid; i < VOCAB; i += 1024) {
        int s = min(4, max(0, (int)floorf(gates_w[i] * 5.0f)));
        loc[s]++;
    }
#pragma unroll
    for (int g = 0; g < NG; ++g) if (loc[g]) atomicAdd(&cnt[g], loc[g]);
    __syncthreads();
    if (tid == 0) {
        int p = 0;
#pragma unroll
        for (int g = 0; g < NG; ++g) { pbase[g] = p; p += ((cnt[g] + 127) >> 7) << 7; }
    }
    __syncthreads();
    for (int c = 0; c < 32; ++c) {
        int i = c * 1024 + tid;
        int s = -1;
        if (i < VOCAB) s = min(4, max(0, (int)floorf(gates_w[i] * 5.0f)));
        int myrank = 0;
#pragma unroll
        for (int g = 0; g < NG; ++g) {
            unsigned long long m = __ballot(s == g);
            if (lane == 0) wtot[wv][g] = (int)__popcll(m);
            if (s == g) myrank = (int)__popcll(m & ((1ull << lane) - 1ull));
        }
        __syncthreads();
        if (tid < NG) {
            int a = 0;
            for (int w = 0; w < 16; ++w) { wpre[w][tid] = a; a += wtot[w][tid]; }
            ctot[tid] = a;
        }
        __syncthreads();
        if (s >= 0) {
            int p = pbase[s] + runbase[s] + wpre[wv][s] + myrank;
            pos[i] = p;
            jlist[p] = i;
        }
        __syncthreads();
        if (tid < NG) runbase[tid] += ctot[tid];
        __syncthreads();
    }
    // pad slots -> -1 (no memset needed)
#pragma unroll
    for (int g = 0; g < NG; ++g) {
        int s0 = pbase[g] + cnt[g];
        int e0 = pbase[g] + (((cnt[g] + 127) >> 7) << 7);
        for (int p = s0 + tid; p < e0; p += 1024) jlist[p] = -1;
    }
    if (tid == 0) {
        const int kmaxs[NG] = {256, 448, 640, 832, 1024};  // ceil group gate bound to 64
        int t = 0;
        for (int g = 0; g < NG; ++g) {
            int nt = (cnt[g] + 127) >> 7;
            for (int k = 0; k < nt; ++k) { tdesc[t] = make_int4(g, pbase[g] + (k << 7), kmaxs[g], 0); ++t; }
        }
        for (; t < MAXTILES; ++t) tdesc[t] = make_int4(-1, 0, 0, 0);
    }
}

// ---------------- f32 -> bf16 convert (vectorized) --------------------------
__global__ void conv_kernel(const float* __restrict__ in, unsigned short* __restrict__ out, int n4) {
    int i = blockIdx.x * blockDim.x + threadIdx.x;
    if (i >= n4) return;
    const float4 f = ((const float4*)in)[i];
    ushort4 o;
    o.x = f2bf(f.x); o.y = f2bf(f.y); o.z = f2bf(f.z); o.w = f2bf(f.w);
    ((ushort4*)out)[i] = o;
}

// -------- masked weight: transpose [d][v] -> [pos[v]][d], bf16 --------------
__global__ __launch_bounds__(256) void wm_kernel(const float* __restrict__ weight,
                                                 const float* __restrict__ gates_w,
                                                 const int* __restrict__ pos,
                                                 unsigned short* __restrict__ wmbp) {
    __shared__ unsigned short tl[64][68];
    __shared__ float gatev[64];
    __shared__ int posv[64];
    const int v0 = blockIdx.x * 64, d0 = blockIdx.y * 64;
    const int tid = threadIdx.x;
    if (tid < 64) { gatev[tid] = gates_w[v0 + tid] * 1024.0f; posv[tid] = pos[v0 + tid]; }
    __syncthreads();
#pragma unroll
    for (int it = 0; it < 16; ++it) {
        int idx = it * 256 + tid;
        int ld = idx >> 6, lv = idx & 63;
        float w = weight[(size_t)(d0 + ld) * VOCAB + (v0 + lv)];
        float m = ((float)(d0 + ld) < gatev[lv]) ? 1.0f : 0.0f;
        tl[lv][ld] = f2bf(w * m);
    }
    __syncthreads();
#pragma unroll
    for (int it = 0; it < 2; ++it) {
        int idx = it * 256 + tid;
        int lv = idx >> 3, ch = idx & 7;
        union { unsigned short u[8]; uint4 q; } uu;
#pragma unroll
        for (int k = 0; k < 8; ++k) uu.u[k] = tl[lv][ch * 8 + k];
        *(uint4*)(wmbp + (size_t)posv[lv] * DIM + d0 + ch * 8) = uu.q;
    }
}

// ---------------- transform GEMM: y_g = x @ blk_w[g]^T + blk_b[g] -----------
// A = xbf [4096][1024], Bt = wbf [5120][1024], C -> ybf[g][t][e] bf16
__global__ __launch_bounds__(256, 2) void tf_gemm(const unsigned short* __restrict__ xbf,
                                                  const unsigned short* __restrict__ wbf,
                                                  const float* __restrict__ blk_b,
                                                  unsigned short* __restrict__ ybf) {
    __shared__ __align__(16) unsigned short lA[128 * 64];
    __shared__ __align__(16) unsigned short lB[128 * 64];
    const int tid = threadIdx.x;
    const int lane = tid & 63, wv = tid >> 6;
    const int wm64 = (wv >> 1) * 64, wn64 = (wv & 1) * 64;
    const int m0 = blockIdx.y * 128, n0 = blockIdx.x * 128;
    const int lr = lane >> 4, lc = lane & 15;
    f32x4 acc[4][4] = {};
    const int r = tid >> 3, c = tid & 7;
    const unsigned short* sa = xbf + (size_t)(m0 + r) * DIM + c * 8;
    const unsigned short* sb = wbf + (size_t)(n0 + r) * DIM + c * 8;
    unsigned short* da = &lA[r * 64 + c * 8];
    unsigned short* db = &lB[r * 64 + c * 8];
    for (int kt = 0; kt < DIM / 64; ++kt) {
#pragma unroll
        for (int s = 0; s < 4; ++s) {
            gload16(sa + (size_t)s * 32 * DIM + kt * 64, da + s * 32 * 64);
            gload16(sb + (size_t)s * 32 * DIM + kt * 64, db + s * 32 * 64);
        }
        __syncthreads();
#pragma unroll
        for (int kk = 0; kk < 64; kk += 32) {
            const int ko = kk + lr * 8;
            bf16x8 af[4], bg[4];
#pragma unroll
            for (int m = 0; m < 4; ++m) af[m] = *(const bf16x8*)&lA[(wm64 + m * 16 + lc) * 64 + ko];
#pragma unroll
            for (int n = 0; n < 4; ++n) bg[n] = *(const bf16x8*)&lB[(wn64 + n * 16 + lc) * 64 + ko];
#pragma unroll
            for (int m = 0; m < 4; ++m)
#pragma unroll
                for (int n = 0; n < 4; ++n)
                    acc[m][n] = __builtin_amdgcn_mfma_f32_16x16x32_bf16(af[m], bg[n], acc[m][n], 0, 0, 0);
        }
        __syncthreads();
    }
#pragma unroll
    for (int n = 0; n < 4; ++n) {
        const int col = n0 + wn64 + n * 16 + lc;
        const float badd = blk_b[col];
        const int g = col >> 10, e = col & 1023;
#pragma unroll
        for (int m = 0; m < 4; ++m) {
            const int t0 = m0 + wm64 + m * 16 + lr * 4;
#pragma unroll
            for (int i = 0; i < 4; ++i)
                ybf[((size_t)g * NTOK + t0 + i) * DIM + e] = f2bf(acc[m][n][i] + badd);
        }
    }
}

// ---------------- main grouped GEMM: out[t][v] = y_g[t,:]·wmbp[j,:] + bias --
__global__ __launch_bounds__(256, 2) void main_gemm(const unsigned short* __restrict__ ybf,
                                                    const unsigned short* __restrict__ wmbp,
                                                    const int* __restrict__ jlist,
                                                    const int4* __restrict__ tdesc,
                                                    const float* __restrict__ bias,
                                                    float* __restrict__ out) {
    const int4 td = tdesc[blockIdx.x];
    if (td.x < 0) return;
    const int g = td.x, jb = td.y, kmax = td.z;
    __shared__ __align__(16) unsigned short lA[128 * 64];
    __shared__ __align__(16) unsigned short lB[128 * 64];
    const int tid = threadIdx.x;
    const int lane = tid & 63, wv = tid >> 6;
    const int wm64 = (wv >> 1) * 64, wn64 = (wv & 1) * 64;
    const int m0 = blockIdx.y * 128;
    const int lr = lane >> 4, lc = lane & 15;
    f32x4 acc[4][4] = {};
    const int r = tid >> 3, c = tid & 7;
    const unsigned short* sa = ybf + (size_t)g * NTOK * DIM + (size_t)(m0 + r) * DIM + c * 8;
    const unsigned short* sb = wmbp + (size_t)(jb + r) * DIM + c * 8;
    unsigned short* da = &lA[r * 64 + c * 8];
    unsigned short* db = &lB[r * 64 + c * 8];
    const int nkt = kmax >> 6;
    for (int kt = 0; kt < nkt; ++kt) {
#pragma unroll
        for (int s = 0; s < 4; ++s) {
            gload16(sa + (size_t)s * 32 * DIM + kt * 64, da + s * 32 * 64);
            gload16(sb + (size_t)s * 32 * DIM + kt * 64, db + s * 32 * 64);
        }
        __syncthreads();
#pragma unroll
        for (int kk = 0; kk < 64; kk += 32) {
            const int ko = kk + lr * 8;
            bf16x8 af[4], bg[4];
#pragma unroll
            for (int m = 0; m < 4; ++m) af[m] = *(const bf16x8*)&lA[(wm64 + m * 16 + lc) * 64 + ko];
#pragma unroll
            for (int n = 0; n < 4; ++n) bg[n] = *(const bf16x8*)&lB[(wn64 + n * 16 + lc) * 64 + ko];
#pragma unroll
            for (int m = 0; m < 4; ++m)
#pragma unroll
                for (int n = 0; n < 4; ++n)
                    acc[m][n] = __builtin_amdgcn_mfma_f32_16x16x32_bf16(af[m], bg[n], acc[m][n], 0, 0, 0);
        }
        __syncthreads();
    }
#pragma unroll
    for (int n = 0; n < 4; ++n) {
        const int p = jb + wn64 + n * 16 + lc;
        const int v = jlist[p];
        if (v < 0) continue;
        const float bv = bias[v];
#pragma unroll
        for (int m = 0; m < 4; ++m) {
            const int t0 = m0 + wm64 + m * 16 + lr * 4;
#pragma unroll
            for (int i = 0; i < 4; ++i)
                out[(size_t)(t0 + i) * VOCAB + v] = acc[m][n][i] + bv;
        }
    }
}

extern "C" void kernel_launch(void* const* d_in, const int* in_sizes, int n_in,
                              void* d_out, int out_size, void* d_ws, size_t ws_size,
                              hipStream_t stream) {
    const float* x       = (const float*)d_in[0];   // [2,2048,1024]
    const float* gates_w = (const float*)d_in[1];   // [32000,1]
    const float* weight  = (const float*)d_in[2];   // [1024,32000]
    const float* bias    = (const float*)d_in[3];   // [32000]
    const float* blk_w   = (const float*)d_in[4];   // [5,1024,1024]
    const float* blk_b   = (const float*)d_in[5];   // [5,1024]
    float* out = (float*)d_out;
    char* ws = (char*)d_ws;

    // workspace layout (bytes)
    unsigned short* xbf   = (unsigned short*)(ws);              //  8,388,608
    unsigned short* wbf   = (unsigned short*)(ws + 8388608);    // 10,485,760
    unsigned short* ybf   = (unsigned short*)(ws + 18874368);   // 41,943,040 (5 x [4096][1024])
    unsigned short* wmbp  = (unsigned short*)(ws + 60817408);   // 66,846,720 (32640 x 1024)
    int*  pos   = (int*)(ws + 127664128);                       // 128,000
    int*  jlist = (int*)(ws + 127792128);                       // 130,560
    int4* tdesc = (int4*)(ws + 127922688);                      // 4,080

    scan_kernel<<<dim3(1), dim3(1024), 0, stream>>>(gates_w, pos, jlist, tdesc);
    conv_kernel<<<dim3(4096), dim3(256), 0, stream>>>(x, xbf, 1048576);
    conv_kernel<<<dim3(5120), dim3(256), 0, stream>>>(blk_w, wbf, 1310720);
    wm_kernel<<<dim3(500, 16), dim3(256), 0, stream>>>(weight, gates_w, pos, wmbp);
    tf_gemm<<<dim3(40, 32), dim3(256), 0, stream>>>(xbf, wbf, blk_b, ybf);
    main_gemm<<<dim3(MAXTILES, 32), dim3(256), 0, stream>>>(ybf, wmbp, jlist, tdesc, bias, out);
}

// Round 4
// 1178.399 us; speedup vs baseline: 1.2862x; 1.2862x over previous
//
#include <hip/hip_runtime.h>
#include <hip/hip_bf16.h>

#define VOCAB 32000
#define DIM 1024
#define NTOK 4096
#define NG 5
#define MAXTILES 255
#define PW 32640  // padded compact width

typedef float f32x4 __attribute__((ext_vector_type(4)));
typedef __bf16 bf16x8 __attribute__((ext_vector_type(8)));

__device__ __forceinline__ unsigned short f2bf(float f) {
    union { float f; unsigned int u; } x; x.f = f;
    unsigned int r = x.u + 0x7fffu + ((x.u >> 16) & 1u);
    return (unsigned short)(r >> 16);
}
__device__ __forceinline__ float bf2f(unsigned short u) {
    union { unsigned int u; float f; } x; x.u = ((unsigned int)u) << 16;
    return x.f;
}

__device__ __forceinline__ void gload16(const void* g, void* l) {
    __builtin_amdgcn_global_load_lds(
        (const __attribute__((address_space(1))) void*)g,
        (__attribute__((address_space(3))) void*)l, 16, 0, 0);
}

// ---------------- scan stage 1: per-block selector histogram ----------------
__global__ __launch_bounds__(256) void hist_kernel(const float* __restrict__ gates_w,
                                                   int* __restrict__ hist) {
    __shared__ int cnt[NG];
    const int tid = threadIdx.x;
    if (tid < NG) cnt[tid] = 0;
    __syncthreads();
    const int v = blockIdx.x * 256 + tid;
    const int s = min(4, max(0, (int)floorf(gates_w[v] * 5.0f)));
    atomicAdd(&cnt[s], 1);
    __syncthreads();
    if (tid < NG) hist[blockIdx.x * NG + tid] = cnt[tid];
}

// ---------------- scan stage 2: bases, tile descriptors, jlist pads ---------
__global__ __launch_bounds__(64) void base_kernel(const int* __restrict__ hist,
                                                  int* __restrict__ blkoff,
                                                  int* __restrict__ jlist,
                                                  int4* __restrict__ tdesc,
                                                  int* __restrict__ pbase6) {
    __shared__ int histl[125 * NG];
    __shared__ int cnt[NG], pb[NG], padc[NG];
    const int tid = threadIdx.x;
    for (int i = tid; i < 125 * NG; i += 64) histl[i] = hist[i];
    __syncthreads();
    if (tid == 0) {
        int c[NG] = {0, 0, 0, 0, 0};
        for (int b = 0; b < 125; ++b)
            for (int g = 0; g < NG; ++g) c[g] += histl[b * NG + g];
        const int kmaxs[NG] = {256, 448, 640, 832, 1024};
        int p = 0, t = 0;
        for (int g = 0; g < NG; ++g) {
            pb[g] = p; cnt[g] = c[g];
            padc[g] = ((c[g] + 127) >> 7) << 7;
            pbase6[g] = p;
            p += padc[g];
        }
        pbase6[NG] = p;
        for (int g = 0; g < NG; ++g) {
            int nt = (cnt[g] + 127) >> 7;
            for (int k = 0; k < nt; ++k) { tdesc[t] = make_int4(g, pb[g] + (k << 7), kmaxs[g], 0); ++t; }
        }
        for (; t < MAXTILES; ++t) tdesc[t] = make_int4(-1, 0, 0, 0);
        int run[NG];
        for (int g = 0; g < NG; ++g) run[g] = pb[g];
        for (int b = 0; b < 125; ++b)
            for (int g = 0; g < NG; ++g) { blkoff[b * NG + g] = run[g]; run[g] += histl[b * NG + g]; }
    }
    __syncthreads();
    for (int g = 0; g < NG; ++g)
        for (int i = pb[g] + cnt[g] + tid; i < pb[g] + padc[g]; i += 64) jlist[i] = -1;
}

// ---------------- scan stage 3: stable positions ----------------------------
__global__ __launch_bounds__(256) void place_kernel(const float* __restrict__ gates_w,
                                                    const int* __restrict__ blkoff,
                                                    int* __restrict__ pos,
                                                    int* __restrict__ jlist) {
    __shared__ int wtot[4][NG], wpre[4][NG];
    const int tid = threadIdx.x, lane = tid & 63, wv = tid >> 6;
    const int v = blockIdx.x * 256 + tid;
    const int s = min(4, max(0, (int)floorf(gates_w[v] * 5.0f)));
    int rank = 0;
#pragma unroll
    for (int g = 0; g < NG; ++g) {
        unsigned long long m = __ballot(s == g);
        if (lane == 0) wtot[wv][g] = (int)__popcll(m);
        if (s == g) rank = (int)__popcll(m & ((1ull << lane) - 1ull));
    }
    __syncthreads();
    if (tid < NG) {
        int a = 0;
        for (int w = 0; w < 4; ++w) { wpre[w][tid] = a; a += wtot[w][tid]; }
    }
    __syncthreads();
    const int p = blkoff[blockIdx.x * NG + s] + wpre[wv][s] + rank;
    pos[v] = p;
    jlist[p] = v;
}

// ---------------- f32 -> bf16 convert (vectorized) --------------------------
__global__ void conv_kernel(const float* __restrict__ in, unsigned short* __restrict__ out, int n4) {
    int i = blockIdx.x * blockDim.x + threadIdx.x;
    if (i >= n4) return;
    const float4 f = ((const float4*)in)[i];
    ushort4 o;
    o.x = f2bf(f.x); o.y = f2bf(f.y); o.z = f2bf(f.z); o.w = f2bf(f.w);
    ((ushort4*)out)[i] = o;
}

// -------- masked weight: transpose [d][v] -> [pos[v]][d], bf16 --------------
__global__ __launch_bounds__(256) void wm_kernel(const float* __restrict__ weight,
                                                 const float* __restrict__ gates_w,
                                                 const int* __restrict__ pos,
                                                 unsigned short* __restrict__ wmbp) {
    __shared__ unsigned short tl[64][68];
    __shared__ float gatev[64];
    __shared__ int posv[64];
    const int v0 = blockIdx.x * 64, d0 = blockIdx.y * 64;
    const int tid = threadIdx.x;
    if (tid < 64) { gatev[tid] = gates_w[v0 + tid] * 1024.0f; posv[tid] = pos[v0 + tid]; }
    __syncthreads();
#pragma unroll
    for (int it = 0; it < 16; ++it) {
        int idx = it * 256 + tid;
        int ld = idx >> 6, lv = idx & 63;
        float w = weight[(size_t)(d0 + ld) * VOCAB + (v0 + lv)];
        float m = ((float)(d0 + ld) < gatev[lv]) ? 1.0f : 0.0f;
        tl[lv][ld] = f2bf(w * m);
    }
    __syncthreads();
#pragma unroll
    for (int it = 0; it < 2; ++it) {
        int idx = it * 256 + tid;
        int lv = idx >> 3, ch = idx & 7;
        union { unsigned short u[8]; uint4 q; } uu;
#pragma unroll
        for (int k = 0; k < 8; ++k) uu.u[k] = tl[lv][ch * 8 + k];
        *(uint4*)(wmbp + (size_t)posv[lv] * DIM + d0 + ch * 8) = uu.q;
    }
}

// ---------------- transform GEMM: y_g = x @ blk_w[g]^T + blk_b[g] -----------
__global__ __launch_bounds__(256, 2) void tf_gemm(const unsigned short* __restrict__ xbf,
                                                  const unsigned short* __restrict__ wbf,
                                                  const float* __restrict__ blk_b,
                                                  unsigned short* __restrict__ ybf) {
    __shared__ __align__(16) unsigned short lA[128 * 64];
    __shared__ __align__(16) unsigned short lB[128 * 64];
    const int tid = threadIdx.x;
    const int lane = tid & 63, wv = tid >> 6;
    const int wm64 = (wv >> 1) * 64, wn64 = (wv & 1) * 64;
    const int m0 = blockIdx.y * 128, n0 = blockIdx.x * 128;
    const int lr = lane >> 4, lc = lane & 15;
    f32x4 acc[4][4] = {};
    const int r = tid >> 3, c = tid & 7;
    const unsigned short* sa = xbf + (size_t)(m0 + r) * DIM + c * 8;
    const unsigned short* sb = wbf + (size_t)(n0 + r) * DIM + c * 8;
    unsigned short* da = &lA[r * 64 + c * 8];
    unsigned short* db = &lB[r * 64 + c * 8];
    for (int kt = 0; kt < DIM / 64; ++kt) {
#pragma unroll
        for (int s = 0; s < 4; ++s) {
            gload16(sa + (size_t)s * 32 * DIM + kt * 64, da + s * 32 * 64);
            gload16(sb + (size_t)s * 32 * DIM + kt * 64, db + s * 32 * 64);
        }
        __syncthreads();
#pragma unroll
        for (int kk = 0; kk < 64; kk += 32) {
            const int ko = kk + lr * 8;
            bf16x8 af[4], bg[4];
#pragma unroll
            for (int m = 0; m < 4; ++m) af[m] = *(const bf16x8*)&lA[(wm64 + m * 16 + lc) * 64 + ko];
#pragma unroll
            for (int n = 0; n < 4; ++n) bg[n] = *(const bf16x8*)&lB[(wn64 + n * 16 + lc) * 64 + ko];
#pragma unroll
            for (int m = 0; m < 4; ++m)
#pragma unroll
                for (int n = 0; n < 4; ++n)
                    acc[m][n] = __builtin_amdgcn_mfma_f32_16x16x32_bf16(af[m], bg[n], acc[m][n], 0, 0, 0);
        }
        __syncthreads();
    }
#pragma unroll
    for (int n = 0; n < 4; ++n) {
        const int col = n0 + wn64 + n * 16 + lc;
        const float badd = blk_b[col];
        const int g = col >> 10, e = col & 1023;
#pragma unroll
        for (int m = 0; m < 4; ++m) {
            const int t0 = m0 + wm64 + m * 16 + lr * 4;
#pragma unroll
            for (int i = 0; i < 4; ++i)
                ybf[((size_t)g * NTOK + t0 + i) * DIM + e] = f2bf(acc[m][n][i] + badd);
        }
    }
}

// ---------------- main grouped GEMM ----------------------------------------
// COMPACT: write bf16 outc[t][p] contiguous. else: direct scattered f32 write.
template <bool COMPACT>
__global__ __launch_bounds__(256, 2) void main_gemm(const unsigned short* __restrict__ ybf,
                                                    const unsigned short* __restrict__ wmbp,
                                                    const int* __restrict__ jlist,
                                                    const int4* __restrict__ tdesc,
                                                    const float* __restrict__ bias,
                                                    float* __restrict__ out,
                                                    unsigned short* __restrict__ outc) {
    // XCD-aware + locality remap: j fastest within m-chunks of 8 (bijective, 8160 = 8*1020)
    const int rid = blockIdx.y * 255 + blockIdx.x;
    const int swz = (rid & 7) * 1020 + (rid >> 3);
    const int mc = swz / 2040;
    const int rem = swz - mc * 2040;
    const int j = rem >> 3;
    const int m0 = (mc * 8 + (rem & 7)) * 128;
    const int4 td = tdesc[j];
    if (td.x < 0) return;
    const int g = td.x, jb = td.y, kmax = td.z;
    __shared__ __align__(16) unsigned short lA[128 * 64];
    __shared__ __align__(16) unsigned short lB[128 * 64];
    const int tid = threadIdx.x;
    const int lane = tid & 63, wv = tid >> 6;
    const int wm64 = (wv >> 1) * 64, wn64 = (wv & 1) * 64;
    const int lr = lane >> 4, lc = lane & 15;
    f32x4 acc[4][4] = {};
    const int r = tid >> 3, c = tid & 7;
    const unsigned short* sa = ybf + (size_t)g * NTOK * DIM + (size_t)(m0 + r) * DIM + c * 8;
    const unsigned short* sb = wmbp + (size_t)(jb + r) * DIM + c * 8;
    unsigned short* da = &lA[r * 64 + c * 8];
    unsigned short* db = &lB[r * 64 + c * 8];
    const int nkt = kmax >> 6;
    for (int kt = 0; kt < nkt; ++kt) {
#pragma unroll
        for (int s = 0; s < 4; ++s) {
            gload16(sa + (size_t)s * 32 * DIM + kt * 64, da + s * 32 * 64);
            gload16(sb + (size_t)s * 32 * DIM + kt * 64, db + s * 32 * 64);
        }
        __syncthreads();
#pragma unroll
        for (int kk = 0; kk < 64; kk += 32) {
            const int ko = kk + lr * 8;
            bf16x8 af[4], bg[4];
#pragma unroll
            for (int m = 0; m < 4; ++m) af[m] = *(const bf16x8*)&lA[(wm64 + m * 16 + lc) * 64 + ko];
#pragma unroll
            for (int n = 0; n < 4; ++n) bg[n] = *(const bf16x8*)&lB[(wn64 + n * 16 + lc) * 64 + ko];
#pragma unroll
            for (int m = 0; m < 4; ++m)
#pragma unroll
                for (int n = 0; n < 4; ++n)
                    acc[m][n] = __builtin_amdgcn_mfma_f32_16x16x32_bf16(af[m], bg[n], acc[m][n], 0, 0, 0);
        }
        __syncthreads();
    }
    if (COMPACT) {
#pragma unroll
        for (int n = 0; n < 4; ++n) {
            const int p = jb + wn64 + n * 16 + lc;
#pragma unroll
            for (int m = 0; m < 4; ++m) {
                const int t0 = m0 + wm64 + m * 16 + lr * 4;
#pragma unroll
                for (int i = 0; i < 4; ++i)
                    outc[(size_t)(t0 + i) * PW + p] = f2bf(acc[m][n][i]);
            }
        }
    } else {
#pragma unroll
        for (int n = 0; n < 4; ++n) {
            const int p = jb + wn64 + n * 16 + lc;
            const int v = jlist[p];
            if (v < 0) continue;
            const float bv = bias[v];
#pragma unroll
            for (int m = 0; m < 4; ++m) {
                const int t0 = m0 + wm64 + m * 16 + lr * 4;
#pragma unroll
                for (int i = 0; i < 4; ++i)
                    out[(size_t)(t0 + i) * VOCAB + v] = acc[m][n][i] + bv;
            }
        }
    }
}

// ---------------- permute: out[t][v] = f32(outc[t][pos[v]]) + bias[v] -------
// Block: 1024 v-cols x 16 t-rows. Consecutive v of one group have consecutive
// pos -> exactly 5 contiguous p-windows per block; stage them in LDS.
__global__ __launch_bounds__(256) void permute_kernel(const unsigned short* __restrict__ outc,
                                                      const int* __restrict__ pos,
                                                      const float* __restrict__ bias,
                                                      const int* __restrict__ pbase6,
                                                      float* __restrict__ out) {
    __shared__ __align__(16) unsigned short tile[16][1152];
    __shared__ unsigned short pidx[1024];
    __shared__ float biasl[1024];
    __shared__ int pminS[NG], cntS[NG], baseS[NG], astartS[NG], alenS[NG];
    __shared__ int pb[NG + 1];
    const int tid = threadIdx.x;
    const int v0 = blockIdx.x * 1024;
    const int t0 = blockIdx.y * 16;
    const int vcnt = min(1024, VOCAB - v0);
    if (tid < NG) { pminS[tid] = 0x7fffffff; cntS[tid] = 0; }
    if (tid < NG + 1) pb[tid] = pbase6[tid];
    __syncthreads();
    // classify, per-group min/count
    for (int i = tid; i < vcnt; i += 256) {
        int p = pos[v0 + i];
        int g = 0;
#pragma unroll
        for (int gg = 1; gg < NG; ++gg) if (p >= pb[gg]) g = gg;
        atomicMin(&pminS[g], p);
        atomicAdd(&cntS[g], 1);
    }
    __syncthreads();
    if (tid == 0) {
        int b = 0;
#pragma unroll
        for (int g = 0; g < NG; ++g) {
            int c = cntS[g];
            int as = (c > 0) ? (pminS[g] & ~7) : 0;
            int al = (c > 0) ? (((pminS[g] + c + 7) & ~7) - as) : 0;
            astartS[g] = as; alenS[g] = al; baseS[g] = b; b += al;
        }
    }
    __syncthreads();
    // local indices + bias
    for (int i = tid; i < vcnt; i += 256) {
        int p = pos[v0 + i];
        int g = 0;
#pragma unroll
        for (int gg = 1; gg < NG; ++gg) if (p >= pb[gg]) g = gg;
        pidx[i] = (unsigned short)(baseS[g] + (p - astartS[g]));
        biasl[i] = bias[v0 + i];
    }
    // stage the 5 windows (vectorized, 8-aligned)
#pragma unroll
    for (int g = 0; g < NG; ++g) {
        const int al8 = alenS[g] >> 3;
        const int as = astartS[g], bs = baseS[g];
        for (int w = tid; w < 16 * al8; w += 256) {
            const int t = w / al8, k = w - t * al8;
            *(uint4*)&tile[t][bs + k * 8] =
                *(const uint4*)&outc[(size_t)(t0 + t) * PW + as + k * 8];
        }
    }
    __syncthreads();
    // gather from LDS, add bias, coalesced f32x4 store
    for (int w = tid; w < 16 * 256; w += 256) {
        const int t = w >> 8, i = (w & 255) * 4;
        if (i >= vcnt) continue;
        float4 o;
        o.x = bf2f(tile[t][pidx[i + 0]]) + biasl[i + 0];
        o.y = bf2f(tile[t][pidx[i + 1]]) + biasl[i + 1];
        o.z = bf2f(tile[t][pidx[i + 2]]) + biasl[i + 2];
        o.w = bf2f(tile[t][pidx[i + 3]]) + biasl[i + 3];
        *(float4*)&out[(size_t)(t0 + t) * VOCAB + v0 + i] = o;
    }
}

extern "C" void kernel_launch(void* const* d_in, const int* in_sizes, int n_in,
                              void* d_out, int out_size, void* d_ws, size_t ws_size,
                              hipStream_t stream) {
    const float* x       = (const float*)d_in[0];
    const float* gates_w = (const float*)d_in[1];
    const float* weight  = (const float*)d_in[2];
    const float* bias    = (const float*)d_in[3];
    const float* blk_w   = (const float*)d_in[4];
    const float* blk_b   = (const float*)d_in[5];
    float* out = (float*)d_out;
    char* ws = (char*)d_ws;

    unsigned short* xbf    = (unsigned short*)(ws);
    unsigned short* wbf    = (unsigned short*)(ws + 8388608);
    unsigned short* ybf    = (unsigned short*)(ws + 18874368);
    unsigned short* wmbp   = (unsigned short*)(ws + 60817408);
    int*  pos    = (int*)(ws + 127664128);
    int*  jlist  = (int*)(ws + 127792128);
    int4* tdesc  = (int4*)(ws + 127922688);
    int*  pbase6 = (int*)(ws + 127926768);
    int*  hist   = (int*)(ws + 127926792);
    int*  blkoff = (int*)(ws + 127929292);
    unsigned short* outc = (unsigned short*)(ws + 127931904);
    const bool compact = (ws_size >= 395318784ull);

    hist_kernel<<<dim3(125), dim3(256), 0, stream>>>(gates_w, hist);
    base_kernel<<<dim3(1), dim3(64), 0, stream>>>(hist, blkoff, jlist, tdesc, pbase6);
    place_kernel<<<dim3(125), dim3(256), 0, stream>>>(gates_w, blkoff, pos, jlist);
    conv_kernel<<<dim3(4096), dim3(256), 0, stream>>>(x, xbf, 1048576);
    conv_kernel<<<dim3(5120), dim3(256), 0, stream>>>(blk_w, wbf, 1310720);
    wm_kernel<<<dim3(500, 16), dim3(256), 0, stream>>>(weight, gates_w, pos, wmbp);
    tf_gemm<<<dim3(40, 32), dim3(256), 0, stream>>>(xbf, wbf, blk_b, ybf);
    if (compact) {
        main_gemm<true><<<dim3(MAXTILES, 32), dim3(256), 0, stream>>>(ybf, wmbp, jlist, tdesc, bias, out, outc);
        permute_kernel<<<dim3(32, 256), dim3(256), 0, stream>>>(outc, pos, bias, pbase6, out);
    } else {
        main_gemm<false><<<dim3(MAXTILES, 32), dim3(256), 0, stream>>>(ybf, wmbp, jlist, tdesc, bias, out, outc);
    }
}

// Round 6
// 1084.934 us; speedup vs baseline: 1.3970x; 1.0861x over previous
//
#include <hip/hip_runtime.h>
#include <hip/hip_bf16.h>

#define VOCAB 32000
#define DIM 1024
#define NTOK 4096
#define NG 5
#define MAXTILES 255

typedef float f32x4 __attribute__((ext_vector_type(4)));
typedef __bf16 bf16x8 __attribute__((ext_vector_type(8)));

__device__ __forceinline__ unsigned short f2bf(float f) {
    union { float f; unsigned int u; } x; x.f = f;
    unsigned int r = x.u + 0x7fffu + ((x.u >> 16) & 1u);
    return (unsigned short)(r >> 16);
}
__device__ __forceinline__ float bf2f(unsigned short u) {
    union { unsigned int u; float f; } x; x.u = ((unsigned int)u) << 16;
    return x.f;
}

__device__ __forceinline__ void gload16(const void* g, void* l) {
    __builtin_amdgcn_global_load_lds(
        (const __attribute__((address_space(1))) void*)g,
        (__attribute__((address_space(3))) void*)l, 16, 0, 0);
}

// ---------------- scan stage 1: per-block selector histogram ----------------
__global__ __launch_bounds__(256) void hist_kernel(const float* __restrict__ gates_w,
                                                   int* __restrict__ hist) {
    __shared__ int cnt[NG];
    const int tid = threadIdx.x;
    if (tid < NG) cnt[tid] = 0;
    __syncthreads();
    const int v = blockIdx.x * 256 + tid;
    const int s = min(4, max(0, (int)floorf(gates_w[v] * 5.0f)));
    atomicAdd(&cnt[s], 1);
    __syncthreads();
    if (tid < NG) hist[blockIdx.x * NG + tid] = cnt[tid];
}

// ---------------- scan stage 2: bases, tile descriptors, jlist pads ---------
__global__ __launch_bounds__(64) void base_kernel(const int* __restrict__ hist,
                                                  int* __restrict__ blkoff,
                                                  int* __restrict__ jlist,
                                                  int4* __restrict__ tdesc,
                                                  int* __restrict__ pbase6) {
    __shared__ int histl[125 * NG];
    __shared__ int cnt[NG], pb[NG], padc[NG];
    const int tid = threadIdx.x;
    for (int i = tid; i < 125 * NG; i += 64) histl[i] = hist[i];
    __syncthreads();
    if (tid == 0) {
        int c[NG] = {0, 0, 0, 0, 0};
        for (int b = 0; b < 125; ++b)
            for (int g = 0; g < NG; ++g) c[g] += histl[b * NG + g];
        const int kmaxs[NG] = {256, 448, 640, 832, 1024};
        int p = 0, t = 0;
        for (int g = 0; g < NG; ++g) {
            pb[g] = p; cnt[g] = c[g];
            padc[g] = ((c[g] + 127) >> 7) << 7;
            pbase6[g] = p;
            p += padc[g];
        }
        pbase6[NG] = p;
        for (int g = 0; g < NG; ++g) {
            int nt = (cnt[g] + 127) >> 7;
            for (int k = 0; k < nt; ++k) { tdesc[t] = make_int4(g, pb[g] + (k << 7), kmaxs[g], 0); ++t; }
        }
        for (; t < MAXTILES; ++t) tdesc[t] = make_int4(-1, 0, 0, 0);
        int run[NG];
        for (int g = 0; g < NG; ++g) run[g] = pb[g];
        for (int b = 0; b < 125; ++b)
            for (int g = 0; g < NG; ++g) { blkoff[b * NG + g] = run[g]; run[g] += histl[b * NG + g]; }
    }
    __syncthreads();
    for (int g = 0; g < NG; ++g)
        for (int i = pb[g] + cnt[g] + tid; i < pb[g] + padc[g]; i += 64) jlist[i] = -1;
}

// ---------------- scan stage 3: stable positions ----------------------------
__global__ __launch_bounds__(256) void place_kernel(const float* __restrict__ gates_w,
                                                    const int* __restrict__ blkoff,
                                                    int* __restrict__ pos,
                                                    int* __restrict__ jlist) {
    __shared__ int wtot[4][NG], wpre[4][NG];
    const int tid = threadIdx.x, lane = tid & 63, wv = tid >> 6;
    const int v = blockIdx.x * 256 + tid;
    const int s = min(4, max(0, (int)floorf(gates_w[v] * 5.0f)));
    int rank = 0;
#pragma unroll
    for (int g = 0; g < NG; ++g) {
        unsigned long long m = __ballot(s == g);
        if (lane == 0) wtot[wv][g] = (int)__popcll(m);
        if (s == g) rank = (int)__popcll(m & ((1ull << lane) - 1ull));
    }
    __syncthreads();
    if (tid < NG) {
        int a = 0;
        for (int w = 0; w < 4; ++w) { wpre[w][tid] = a; a += wtot[w][tid]; }
    }
    __syncthreads();
    const int p = blkoff[blockIdx.x * NG + s] + wpre[wv][s] + rank;
    pos[v] = p;
    jlist[p] = v;
}

// ---------------- f32 -> bf16 convert (vectorized) --------------------------
__global__ void conv_kernel(const float* __restrict__ in, unsigned short* __restrict__ out, int n4) {
    int i = blockIdx.x * blockDim.x + threadIdx.x;
    if (i >= n4) return;
    const float4 f = ((const float4*)in)[i];
    ushort4 o;
    o.x = f2bf(f.x); o.y = f2bf(f.y); o.z = f2bf(f.z); o.w = f2bf(f.w);
    ((ushort4*)out)[i] = o;
}

// -------- blk_w [g][o][i] f32 -> wbfT [g][i][o] bf16 (transpose) ------------
__global__ __launch_bounds__(256) void convT_kernel(const float* __restrict__ blk_w,
                                                    unsigned short* __restrict__ wbfT) {
    __shared__ unsigned short tl[64][68];
    const int i0 = blockIdx.x * 64, o0 = blockIdx.y * 64, g = blockIdx.z;
    const int tid = threadIdx.x;
    const float* src = blk_w + (size_t)g * DIM * DIM;
    unsigned short* dst = wbfT + (size_t)g * DIM * DIM;
#pragma unroll
    for (int it = 0; it < 16; ++it) {
        int idx = it * 256 + tid;
        int lo = idx >> 6, li = idx & 63;
        tl[li][lo] = f2bf(src[(size_t)(o0 + lo) * DIM + i0 + li]);
    }
    __syncthreads();
#pragma unroll
    for (int it = 0; it < 2; ++it) {
        int idx = it * 256 + tid;
        int ri = idx >> 3, ch = idx & 7;
        union { unsigned short u[8]; uint4 q; } uu;
#pragma unroll
        for (int k = 0; k < 8; ++k) uu.u[k] = tl[ri][ch * 8 + k];
        *(uint4*)(dst + (size_t)(i0 + ri) * DIM + o0 + ch * 8) = uu.q;
    }
}

// -------- masked weight: transpose [o][v] -> [pos[v]][o], bf16 --------------
__global__ __launch_bounds__(256) void wm_kernel(const float* __restrict__ weight,
                                                 const float* __restrict__ gates_w,
                                                 const int* __restrict__ pos,
                                                 unsigned short* __restrict__ wmbp) {
    __shared__ unsigned short tl[64][68];
    __shared__ float gatev[64];
    __shared__ int posv[64];
    const int v0 = blockIdx.x * 64, d0 = blockIdx.y * 64;
    const int tid = threadIdx.x;
    if (tid < 64) { gatev[tid] = gates_w[v0 + tid] * 1024.0f; posv[tid] = pos[v0 + tid]; }
    __syncthreads();
#pragma unroll
    for (int it = 0; it < 16; ++it) {
        int idx = it * 256 + tid;
        int ld = idx >> 6, lv = idx & 63;
        float w = weight[(size_t)(d0 + ld) * VOCAB + (v0 + lv)];
        float m = ((float)(d0 + ld) < gatev[lv]) ? 1.0f : 0.0f;
        tl[lv][ld] = f2bf(w * m);
    }
    __syncthreads();
#pragma unroll
    for (int it = 0; it < 2; ++it) {
        int idx = it * 256 + tid;
        int lv = idx >> 3, ch = idx & 7;
        union { unsigned short u[8]; uint4 q; } uu;
#pragma unroll
        for (int k = 0; k < 8; ++k) uu.u[k] = tl[lv][ch * 8 + k];
        *(uint4*)(wmbp + (size_t)posv[lv] * DIM + d0 + ch * 8) = uu.q;
    }
}

// ---------------- dbias: bias2[v] = bias[v] + dot(b_g, wmbp[p]) -------------
__global__ __launch_bounds__(256) void dbias_kernel(const unsigned short* __restrict__ wmbp,
                                                    const float* __restrict__ blk_b,
                                                    const float* __restrict__ bias,
                                                    const int* __restrict__ jlist,
                                                    const int* __restrict__ pbase6,
                                                    float* __restrict__ bias2) {
    const int p = blockIdx.x * 4 + (threadIdx.x >> 6);
    const int lane = threadIdx.x & 63;
    if (p >= pbase6[NG]) return;
    const int v = jlist[p];
    if (v < 0) return;
    int g = 0;
#pragma unroll
    for (int gg = 1; gg < NG; ++gg) if (p >= pbase6[gg]) g = gg;
    const unsigned short* wrow = wmbp + (size_t)p * DIM + lane * 16;
    const float* brow = blk_b + g * DIM + lane * 16;
    union { uint4 q; unsigned short u[8]; } a0, a1;
    a0.q = *(const uint4*)(wrow);
    a1.q = *(const uint4*)(wrow + 8);
    float s = 0.f;
#pragma unroll
    for (int k = 0; k < 8; ++k) s += bf2f(a0.u[k]) * brow[k];
#pragma unroll
    for (int k = 0; k < 8; ++k) s += bf2f(a1.u[k]) * brow[k + 8];
#pragma unroll
    for (int off = 32; off > 0; off >>= 1) s += __shfl_down(s, off);
    if (lane == 0) bias2[v] = bias[v] + s;
}

// ---------------- ceff GEMM: ceffv[v][i] = sum_o wmbp[p][o] * W_g[o][i] -----
// grouped, K-truncated over o; rows scattered to natural v-order via jlist.
__global__ __launch_bounds__(256, 2) void ceff_gemm(const unsigned short* __restrict__ wmbp,
                                                    const unsigned short* __restrict__ wbfT,
                                                    const int* __restrict__ jlist,
                                                    const int4* __restrict__ tdesc,
                                                    unsigned short* __restrict__ ceffv) {
    const int4 td = tdesc[blockIdx.x];
    if (td.x < 0) return;
    const int g = td.x, jb = td.y, kmax = td.z;
    const int n0 = blockIdx.y * 128;  // i-tile
    __shared__ __align__(16) unsigned short lA[128 * 64];
    __shared__ __align__(16) unsigned short lB[128 * 64];
    const int tid = threadIdx.x;
    const int lane = tid & 63, wv = tid >> 6;
    const int wm64 = (wv >> 1) * 64, wn64 = (wv & 1) * 64;
    const int lr = lane >> 4, lc = lane & 15;
    f32x4 acc[4][4] = {};
    const int r = tid >> 3, c = tid & 7;
    const unsigned short* sa = wmbp + (size_t)(jb + r) * DIM + c * 8;
    const unsigned short* sb = wbfT + (size_t)g * DIM * DIM + (size_t)(n0 + r) * DIM + c * 8;
    unsigned short* da = &lA[r * 64 + c * 8];
    unsigned short* db = &lB[r * 64 + c * 8];
    const int nkt = kmax >> 6;
    for (int kt = 0; kt < nkt; ++kt) {
#pragma unroll
        for (int s = 0; s < 4; ++s) {
            gload16(sa + (size_t)s * 32 * DIM + kt * 64, da + s * 32 * 64);
            gload16(sb + (size_t)s * 32 * DIM + kt * 64, db + s * 32 * 64);
        }
        __syncthreads();
#pragma unroll
        for (int kk = 0; kk < 64; kk += 32) {
            const int ko = kk + lr * 8;
            bf16x8 af[4], bg[4];
#pragma unroll
            for (int m = 0; m < 4; ++m) af[m] = *(const bf16x8*)&lA[(wm64 + m * 16 + lc) * 64 + ko];
#pragma unroll
            for (int n = 0; n < 4; ++n) bg[n] = *(const bf16x8*)&lB[(wn64 + n * 16 + lc) * 64 + ko];
#pragma unroll
            for (int m = 0; m < 4; ++m)
#pragma unroll
                for (int n = 0; n < 4; ++n)
                    acc[m][n] = __builtin_amdgcn_mfma_f32_16x16x32_bf16(af[m], bg[n], acc[m][n], 0, 0, 0);
        }
        __syncthreads();
    }
#pragma unroll
    for (int m = 0; m < 4; ++m) {
#pragma unroll
        for (int i = 0; i < 4; ++i) {
            const int prow = jb + wm64 + m * 16 + lr * 4 + i;
            const int v = jlist[prow];
            if (v < 0) continue;
#pragma unroll
            for (int n = 0; n < 4; ++n) {
                const int icol = n0 + wn64 + n * 16 + lc;
                ceffv[(size_t)v * DIM + icol] = f2bf(acc[m][n][i]);
            }
        }
    }
}

// ---------------- main dense GEMM: out = x . ceff^T + bias2 -----------------
__global__ __launch_bounds__(256, 2) void out_gemm(const unsigned short* __restrict__ xbf,
                                                   const unsigned short* __restrict__ ceffv,
                                                   const float* __restrict__ bias2,
                                                   float* __restrict__ out) {
    // XCD swizzle (8000 = 8*1000) + m-fast within XCD chunk for B-panel L2 reuse
    const int rid = blockIdx.y * gridDim.x + blockIdx.x;
    const int swz = (rid & 7) * 1000 + (rid >> 3);
    const int m0 = (swz & 31) * 128;
    const int n0 = (swz >> 5) * 128;
    __shared__ __align__(16) unsigned short lA[128 * 64];
    __shared__ __align__(16) unsigned short lB[128 * 64];
    const int tid = threadIdx.x;
    const int lane = tid & 63, wv = tid >> 6;
    const int wm64 = (wv >> 1) * 64, wn64 = (wv & 1) * 64;
    const int lr = lane >> 4, lc = lane & 15;
    f32x4 acc[4][4] = {};
    const int r = tid >> 3, c = tid & 7;
    const unsigned short* sa = xbf + (size_t)(m0 + r) * DIM + c * 8;
    const unsigned short* sb = ceffv + (size_t)(n0 + r) * DIM + c * 8;
    unsigned short* da = &lA[r * 64 + c * 8];
    unsigned short* db = &lB[r * 64 + c * 8];
    for (int kt = 0; kt < DIM / 64; ++kt) {
#pragma unroll
        for (int s = 0; s < 4; ++s) {
            gload16(sa + (size_t)s * 32 * DIM + kt * 64, da + s * 32 * 64);
            gload16(sb + (size_t)s * 32 * DIM + kt * 64, db + s * 32 * 64);
        }
        __syncthreads();
#pragma unroll
        for (int kk = 0; kk < 64; kk += 32) {
            const int ko = kk + lr * 8;
            bf16x8 af[4], bg[4];
#pragma unroll
            for (int m = 0; m < 4; ++m) af[m] = *(const bf16x8*)&lA[(wm64 + m * 16 + lc) * 64 + ko];
#pragma unroll
            for (int n = 0; n < 4; ++n) bg[n] = *(const bf16x8*)&lB[(wn64 + n * 16 + lc) * 64 + ko];
#pragma unroll
            for (int m = 0; m < 4; ++m)
#pragma unroll
                for (int n = 0; n < 4; ++n)
                    acc[m][n] = __builtin_amdgcn_mfma_f32_16x16x32_bf16(af[m], bg[n], acc[m][n], 0, 0, 0);
        }
        __syncthreads();
    }
#pragma unroll
    for (int n = 0; n < 4; ++n) {
        const int col = n0 + wn64 + n * 16 + lc;
        const float b2 = bias2[col];
#pragma unroll
        for (int m = 0; m < 4; ++m) {
            const int t0 = m0 + wm64 + m * 16 + lr * 4;
#pragma unroll
            for (int i = 0; i < 4; ++i)
                out[(size_t)(t0 + i) * VOCAB + col] = acc[m][n][i] + b2;
        }
    }
}

extern "C" void kernel_launch(void* const* d_in, const int* in_sizes, int n_in,
                              void* d_out, int out_size, void* d_ws, size_t ws_size,
                              hipStream_t stream) {
    const float* x       = (const float*)d_in[0];   // [2,2048,1024]
    const float* gates_w = (const float*)d_in[1];   // [32000,1]
    const float* weight  = (const float*)d_in[2];   // [1024,32000]
    const float* bias    = (const float*)d_in[3];   // [32000]
    const float* blk_w   = (const float*)d_in[4];   // [5,1024,1024]
    const float* blk_b   = (const float*)d_in[5];   // [5,1024]
    float* out = (float*)d_out;
    char* ws = (char*)d_ws;

    // workspace layout (bytes)
    unsigned short* xbf   = (unsigned short*)(ws);              //  8,388,608
    unsigned short* wbfT  = (unsigned short*)(ws + 8388608);    // 10,485,760
    unsigned short* wmbp  = (unsigned short*)(ws + 18874368);   // 66,846,720 (32640 x 1024)
    unsigned short* ceffv = (unsigned short*)(ws + 85721088);   // 65,536,000 (32000 x 1024)
    float* bias2 = (float*)(ws + 151257088);                    // 128,000
    int*   pos   = (int*)(ws + 151385088);                      // 128,000
    int*   jlist = (int*)(ws + 151513088);                      // 130,560
    int4*  tdesc = (int4*)(ws + 151643648);                     // 4,080
    int*   pbase6 = (int*)(ws + 151647728);                     // 24
    int*   hist   = (int*)(ws + 151647752);                     // 2,500
    int*   blkoff = (int*)(ws + 151650252);                     // 2,500

    hist_kernel<<<dim3(125), dim3(256), 0, stream>>>(gates_w, hist);
    base_kernel<<<dim3(1), dim3(64), 0, stream>>>(hist, blkoff, jlist, tdesc, pbase6);
    place_kernel<<<dim3(125), dim3(256), 0, stream>>>(gates_w, blkoff, pos, jlist);
    conv_kernel<<<dim3(4096), dim3(256), 0, stream>>>(x, xbf, 1048576);
    convT_kernel<<<dim3(16, 16, NG), dim3(256), 0, stream>>>(blk_w, wbfT);
    wm_kernel<<<dim3(500, 16), dim3(256), 0, stream>>>(weight, gates_w, pos, wmbp);
    dbias_kernel<<<dim3(8160), dim3(256), 0, stream>>>(wmbp, blk_b, bias, jlist, pbase6, bias2);
    ceff_gemm<<<dim3(MAXTILES, 8), dim3(256), 0, stream>>>(wmbp, wbfT, jlist, tdesc, ceffv);
    out_gemm<<<dim3(250, 32), dim3(256), 0, stream>>>(xbf, ceffv, bias2, out);
}

// Round 8
// 1031.251 us; speedup vs baseline: 1.4697x; 1.0521x over previous
//
#include <hip/hip_runtime.h>
#include <hip/hip_bf16.h>

#define VOCAB 32000
#define DIM 1024
#define NTOK 4096
#define NG 5
#define MAXTILES 255

typedef float f32x4 __attribute__((ext_vector_type(4)));
typedef __bf16 bf16x8 __attribute__((ext_vector_type(8)));

__device__ __forceinline__ unsigned short f2bf(float f) {
    union { float f; unsigned int u; } x; x.f = f;
    unsigned int r = x.u + 0x7fffu + ((x.u >> 16) & 1u);
    return (unsigned short)(r >> 16);
}
__device__ __forceinline__ float bf2f(unsigned short u) {
    union { unsigned int u; float f; } x; x.u = ((unsigned int)u) << 16;
    return x.f;
}

__device__ __forceinline__ void gload16(const void* g, void* l) {
    __builtin_amdgcn_global_load_lds(
        (const __attribute__((address_space(1))) void*)g,
        (__attribute__((address_space(3))) void*)l, 16, 0, 0);
}

// ---------------- scan stage 1: per-block selector histogram ----------------
__global__ __launch_bounds__(256) void hist_kernel(const float* __restrict__ gates_w,
                                                   int* __restrict__ hist) {
    __shared__ int cnt[NG];
    const int tid = threadIdx.x;
    if (tid < NG) cnt[tid] = 0;
    __syncthreads();
    const int v = blockIdx.x * 256 + tid;
    const int s = min(4, max(0, (int)floorf(gates_w[v] * 5.0f)));
    atomicAdd(&cnt[s], 1);
    __syncthreads();
    if (tid < NG) hist[blockIdx.x * NG + tid] = cnt[tid];
}

// ---------------- scan stage 2: bases, tile descriptors, jlist pads ---------
__global__ __launch_bounds__(64) void base_kernel(const int* __restrict__ hist,
                                                  int* __restrict__ blkoff,
                                                  int* __restrict__ jlist,
                                                  int4* __restrict__ tdesc,
                                                  int* __restrict__ pbase6) {
    __shared__ int histl[125 * NG];
    __shared__ int cnt[NG], pb[NG], padc[NG];
    const int tid = threadIdx.x;
    for (int i = tid; i < 125 * NG; i += 64) histl[i] = hist[i];
    __syncthreads();
    if (tid == 0) {
        int c[NG] = {0, 0, 0, 0, 0};
        for (int b = 0; b < 125; ++b)
            for (int g = 0; g < NG; ++g) c[g] += histl[b * NG + g];
        const int kmaxs[NG] = {256, 448, 640, 832, 1024};
        int p = 0, t = 0;
        for (int g = 0; g < NG; ++g) {
            pb[g] = p; cnt[g] = c[g];
            padc[g] = ((c[g] + 127) >> 7) << 7;
            pbase6[g] = p;
            p += padc[g];
        }
        pbase6[NG] = p;
        for (int g = 0; g < NG; ++g) {
            int nt = (cnt[g] + 127) >> 7;
            for (int k = 0; k < nt; ++k) { tdesc[t] = make_int4(g, pb[g] + (k << 7), kmaxs[g], 0); ++t; }
        }
        for (; t < MAXTILES; ++t) tdesc[t] = make_int4(-1, 0, 0, 0);
        int run[NG];
        for (int g = 0; g < NG; ++g) run[g] = pb[g];
        for (int b = 0; b < 125; ++b)
            for (int g = 0; g < NG; ++g) { blkoff[b * NG + g] = run[g]; run[g] += histl[b * NG + g]; }
    }
    __syncthreads();
    for (int g = 0; g < NG; ++g)
        for (int i = pb[g] + cnt[g] + tid; i < pb[g] + padc[g]; i += 64) jlist[i] = -1;
}

// ---------------- scan stage 3: stable positions ----------------------------
__global__ __launch_bounds__(256) void place_kernel(const float* __restrict__ gates_w,
                                                    const int* __restrict__ blkoff,
                                                    int* __restrict__ pos,
                                                    int* __restrict__ jlist) {
    __shared__ int wtot[4][NG], wpre[4][NG];
    const int tid = threadIdx.x, lane = tid & 63, wv = tid >> 6;
    const int v = blockIdx.x * 256 + tid;
    const int s = min(4, max(0, (int)floorf(gates_w[v] * 5.0f)));
    int rank = 0;
#pragma unroll
    for (int g = 0; g < NG; ++g) {
        unsigned long long m = __ballot(s == g);
        if (lane == 0) wtot[wv][g] = (int)__popcll(m);
        if (s == g) rank = (int)__popcll(m & ((1ull << lane) - 1ull));
    }
    __syncthreads();
    if (tid < NG) {
        int a = 0;
        for (int w = 0; w < 4; ++w) { wpre[w][tid] = a; a += wtot[w][tid]; }
    }
    __syncthreads();
    const int p = blkoff[blockIdx.x * NG + s] + wpre[wv][s] + rank;
    pos[v] = p;
    jlist[p] = v;
}

// ---------------- f32 -> bf16 convert (vectorized) --------------------------
__global__ void conv_kernel(const float* __restrict__ in, unsigned short* __restrict__ out, int n4) {
    int i = blockIdx.x * blockDim.x + threadIdx.x;
    if (i >= n4) return;
    const float4 f = ((const float4*)in)[i];
    ushort4 o;
    o.x = f2bf(f.x); o.y = f2bf(f.y); o.z = f2bf(f.z); o.w = f2bf(f.w);
    ((ushort4*)out)[i] = o;
}

// -------- blk_w [g][o][i] f32 -> wbfT [g][i][o] bf16 (transpose, f32x4 ld) --
__global__ __launch_bounds__(256) void convT_kernel(const float* __restrict__ blk_w,
                                                    unsigned short* __restrict__ wbfT) {
    __shared__ unsigned short tl[64][68];
    const int i0 = blockIdx.x * 64, o0 = blockIdx.y * 64, g = blockIdx.z;
    const int tid = threadIdx.x;
    const float* src = blk_w + (size_t)g * DIM * DIM;
    unsigned short* dst = wbfT + (size_t)g * DIM * DIM;
#pragma unroll
    for (int it = 0; it < 4; ++it) {
        int idx = it * 256 + tid;
        int lo = idx >> 4;            // o-row 0..63
        int c4 = (idx & 15) * 4;      // i-col 0,4,..,60
        float4 w = *(const float4*)&src[(size_t)(o0 + lo) * DIM + i0 + c4];
        tl[c4 + 0][lo] = f2bf(w.x);
        tl[c4 + 1][lo] = f2bf(w.y);
        tl[c4 + 2][lo] = f2bf(w.z);
        tl[c4 + 3][lo] = f2bf(w.w);
    }
    __syncthreads();
#pragma unroll
    for (int it = 0; it < 2; ++it) {
        int idx = it * 256 + tid;
        int ri = idx >> 3, ch = idx & 7;
        union { unsigned short u[8]; uint4 q; } uu;
#pragma unroll
        for (int k = 0; k < 8; ++k) uu.u[k] = tl[ri][ch * 8 + k];
        *(uint4*)(dst + (size_t)(i0 + ri) * DIM + o0 + ch * 8) = uu.q;
    }
}

// -------- masked weight: transpose [o][v] -> [pos[v]][o], bf16 (f32x4 ld) ---
__global__ __launch_bounds__(256) void wm_kernel(const float* __restrict__ weight,
                                                 const float* __restrict__ gates_w,
                                                 const int* __restrict__ pos,
                                                 unsigned short* __restrict__ wmbp) {
    __shared__ unsigned short tl[64][68];
    __shared__ float gatev[64];
    __shared__ int posv[64];
    const int v0 = blockIdx.x * 64, d0 = blockIdx.y * 64;
    const int tid = threadIdx.x;
    if (tid < 64) { gatev[tid] = gates_w[v0 + tid] * 1024.0f; posv[tid] = pos[v0 + tid]; }
    __syncthreads();
#pragma unroll
    for (int it = 0; it < 4; ++it) {
        int idx = it * 256 + tid;
        int ld = idx >> 4;            // d-row 0..63
        int c4 = (idx & 15) * 4;      // v-col 0,4,..,60
        const float dv = (float)(d0 + ld);
        float4 w = *(const float4*)&weight[(size_t)(d0 + ld) * VOCAB + v0 + c4];
        tl[c4 + 0][ld] = f2bf((dv < gatev[c4 + 0]) ? w.x : 0.0f);
        tl[c4 + 1][ld] = f2bf((dv < gatev[c4 + 1]) ? w.y : 0.0f);
        tl[c4 + 2][ld] = f2bf((dv < gatev[c4 + 2]) ? w.z : 0.0f);
        tl[c4 + 3][ld] = f2bf((dv < gatev[c4 + 3]) ? w.w : 0.0f);
    }
    __syncthreads();
#pragma unroll
    for (int it = 0; it < 2; ++it) {
        int idx = it * 256 + tid;
        int lv = idx >> 3, ch = idx & 7;
        union { unsigned short u[8]; uint4 q; } uu;
#pragma unroll
        for (int k = 0; k < 8; ++k) uu.u[k] = tl[lv][ch * 8 + k];
        *(uint4*)(wmbp + (size_t)posv[lv] * DIM + d0 + ch * 8) = uu.q;
    }
}

// ---------------- dbias: bias2[v] = bias[v] + dot(b_g, wmbp[p]) -------------
__global__ __launch_bounds__(256) void dbias_kernel(const unsigned short* __restrict__ wmbp,
                                                    const float* __restrict__ blk_b,
                                                    const float* __restrict__ bias,
                                                    const int* __restrict__ jlist,
                                                    const int* __restrict__ pbase6,
                                                    float* __restrict__ bias2) {
    const int p = blockIdx.x * 4 + (threadIdx.x >> 6);
    const int lane = threadIdx.x & 63;
    if (p >= pbase6[NG]) return;
    const int v = jlist[p];
    if (v < 0) return;
    int g = 0;
#pragma unroll
    for (int gg = 1; gg < NG; ++gg) if (p >= pbase6[gg]) g = gg;
    const unsigned short* wrow = wmbp + (size_t)p * DIM + lane * 16;
    const float* brow = blk_b + g * DIM + lane * 16;
    union { uint4 q; unsigned short u[8]; } a0, a1;
    a0.q = *(const uint4*)(wrow);
    a1.q = *(const uint4*)(wrow + 8);
    float s = 0.f;
#pragma unroll
    for (int k = 0; k < 8; ++k) s += bf2f(a0.u[k]) * brow[k];
#pragma unroll
    for (int k = 0; k < 8; ++k) s += bf2f(a1.u[k]) * brow[k + 8];
#pragma unroll
    for (int off = 32; off > 0; off >>= 1) s += __shfl_down(s, off);
    if (lane == 0) bias2[v] = bias[v] + s;
}

// ---------------- ceff GEMM: ceffv[v][i] = sum_o wmbp[p][o] * W_g[o][i] -----
__global__ __launch_bounds__(256, 2) void ceff_gemm(const unsigned short* __restrict__ wmbp,
                                                    const unsigned short* __restrict__ wbfT,
                                                    const int* __restrict__ jlist,
                                                    const int4* __restrict__ tdesc,
                                                    unsigned short* __restrict__ ceffv) {
    const int4 td = tdesc[blockIdx.x];
    if (td.x < 0) return;
    const int g = td.x, jb = td.y, kmax = td.z;
    const int n0 = blockIdx.y * 128;  // i-tile
    __shared__ __align__(16) unsigned short lA[128 * 64];
    __shared__ __align__(16) unsigned short lB[128 * 64];
    const int tid = threadIdx.x;
    const int lane = tid & 63, wv = tid >> 6;
    const int wm64 = (wv >> 1) * 64, wn64 = (wv & 1) * 64;
    const int lr = lane >> 4, lc = lane & 15;
    f32x4 acc[4][4] = {};
    const int r = tid >> 3, c = tid & 7;
    const unsigned short* sa = wmbp + (size_t)(jb + r) * DIM + c * 8;
    const unsigned short* sb = wbfT + (size_t)g * DIM * DIM + (size_t)(n0 + r) * DIM + c * 8;
    unsigned short* da = &lA[r * 64 + c * 8];
    unsigned short* db = &lB[r * 64 + c * 8];
    const int nkt = kmax >> 6;
    for (int kt = 0; kt < nkt; ++kt) {
#pragma unroll
        for (int s = 0; s < 4; ++s) {
            gload16(sa + (size_t)s * 32 * DIM + kt * 64, da + s * 32 * 64);
            gload16(sb + (size_t)s * 32 * DIM + kt * 64, db + s * 32 * 64);
        }
        __syncthreads();
#pragma unroll
        for (int kk = 0; kk < 64; kk += 32) {
            const int ko = kk + lr * 8;
            bf16x8 af[4], bg[4];
#pragma unroll
            for (int m = 0; m < 4; ++m) af[m] = *(const bf16x8*)&lA[(wm64 + m * 16 + lc) * 64 + ko];
#pragma unroll
            for (int n = 0; n < 4; ++n) bg[n] = *(const bf16x8*)&lB[(wn64 + n * 16 + lc) * 64 + ko];
#pragma unroll
            for (int m = 0; m < 4; ++m)
#pragma unroll
                for (int n = 0; n < 4; ++n)
                    acc[m][n] = __builtin_amdgcn_mfma_f32_16x16x32_bf16(af[m], bg[n], acc[m][n], 0, 0, 0);
        }
        __syncthreads();
    }
#pragma unroll
    for (int m = 0; m < 4; ++m) {
#pragma unroll
        for (int i = 0; i < 4; ++i) {
            const int prow = jb + wm64 + m * 16 + lr * 4 + i;
            const int v = jlist[prow];
            if (v < 0) continue;
#pragma unroll
            for (int n = 0; n < 4; ++n) {
                const int icol = n0 + wn64 + n * 16 + lc;
                ceffv[(size_t)v * DIM + icol] = f2bf(acc[m][n][i]);
            }
        }
    }
}

// ---------------- main dense GEMM: out = x . ceff^T + bias2 -----------------
// nt stores: keep the 524 MB write stream out of L2/L3 so A/B stay resident.
__global__ __launch_bounds__(256, 4) void out_gemm(const unsigned short* __restrict__ xbf,
                                                   const unsigned short* __restrict__ ceffv,
                                                   const float* __restrict__ bias2,
                                                   float* __restrict__ out) {
    // XCD swizzle (8000 = 8*1000) + m-fast within XCD chunk for B-panel L2 reuse
    const int rid = blockIdx.y * gridDim.x + blockIdx.x;
    const int swz = (rid & 7) * 1000 + (rid >> 3);
    const int m0 = (swz & 31) * 128;
    const int n0 = (swz >> 5) * 128;
    __shared__ __align__(16) unsigned short lA[128 * 64];
    __shared__ __align__(16) unsigned short lB[128 * 64];
    const int tid = threadIdx.x;
    const int lane = tid & 63, wv = tid >> 6;
    const int wm64 = (wv >> 1) * 64, wn64 = (wv & 1) * 64;
    const int lr = lane >> 4, lc = lane & 15;
    f32x4 acc[4][4] = {};
    const int r = tid >> 3, c = tid & 7;
    const unsigned short* sa = xbf + (size_t)(m0 + r) * DIM + c * 8;
    const unsigned short* sb = ceffv + (size_t)(n0 + r) * DIM + c * 8;
    unsigned short* da = &lA[r * 64 + c * 8];
    unsigned short* db = &lB[r * 64 + c * 8];
    for (int kt = 0; kt < DIM / 64; ++kt) {
#pragma unroll
        for (int s = 0; s < 4; ++s) {
            gload16(sa + (size_t)s * 32 * DIM + kt * 64, da + s * 32 * 64);
            gload16(sb + (size_t)s * 32 * DIM + kt * 64, db + s * 32 * 64);
        }
        __syncthreads();
#pragma unroll
        for (int kk = 0; kk < 64; kk += 32) {
            const int ko = kk + lr * 8;
            bf16x8 af[4], bg[4];
#pragma unroll
            for (int m = 0; m < 4; ++m) af[m] = *(const bf16x8*)&lA[(wm64 + m * 16 + lc) * 64 + ko];
#pragma unroll
            for (int n = 0; n < 4; ++n) bg[n] = *(const bf16x8*)&lB[(wn64 + n * 16 + lc) * 64 + ko];
#pragma unroll
            for (int m = 0; m < 4; ++m)
#pragma unroll
                for (int n = 0; n < 4; ++n)
                    acc[m][n] = __builtin_amdgcn_mfma_f32_16x16x32_bf16(af[m], bg[n], acc[m][n], 0, 0, 0);
        }
        __syncthreads();
    }
#pragma unroll
    for (int n = 0; n < 4; ++n) {
        const int col = n0 + wn64 + n * 16 + lc;
        const float b2 = bias2[col];
#pragma unroll
        for (int m = 0; m < 4; ++m) {
            const int t0 = m0 + wm64 + m * 16 + lr * 4;
#pragma unroll
            for (int i = 0; i < 4; ++i)
                __builtin_nontemporal_store(acc[m][n][i] + b2,
                                            &out[(size_t)(t0 + i) * VOCAB + col]);
        }
    }
}

extern "C" void kernel_launch(void* const* d_in, const int* in_sizes, int n_in,
                              void* d_out, int out_size, void* d_ws, size_t ws_size,
                              hipStream_t stream) {
    const float* x       = (const float*)d_in[0];   // [2,2048,1024]
    const float* gates_w = (const float*)d_in[1];   // [32000,1]
    const float* weight  = (const float*)d_in[2];   // [1024,32000]
    const float* bias    = (const float*)d_in[3];   // [32000]
    const float* blk_w   = (const float*)d_in[4];   // [5,1024,1024]
    const float* blk_b   = (const float*)d_in[5];   // [5,1024]
    float* out = (float*)d_out;
    char* ws = (char*)d_ws;

    // workspace layout (bytes)
    unsigned short* xbf   = (unsigned short*)(ws);              //  8,388,608
    unsigned short* wbfT  = (unsigned short*)(ws + 8388608);    // 10,485,760
    unsigned short* wmbp  = (unsigned short*)(ws + 18874368);   // 66,846,720 (32640 x 1024)
    unsigned short* ceffv = (unsigned short*)(ws + 85721088);   // 65,536,000 (32000 x 1024)
    float* bias2 = (float*)(ws + 151257088);                    // 128,000
    int*   pos   = (int*)(ws + 151385088);                      // 128,000
    int*   jlist = (int*)(ws + 151513088);                      // 130,560
    int4*  tdesc = (int4*)(ws + 151643648);                     // 4,080
    int*   pbase6 = (int*)(ws + 151647728);                     // 24
    int*   hist   = (int*)(ws + 151647752);                     // 2,500
    int*   blkoff = (int*)(ws + 151650252);                     // 2,500

    hist_kernel<<<dim3(125), dim3(256), 0, stream>>>(gates_w, hist);
    base_kernel<<<dim3(1), dim3(64), 0, stream>>>(hist, blkoff, jlist, tdesc, pbase6);
    place_kernel<<<dim3(125), dim3(256), 0, stream>>>(gates_w, blkoff, pos, jlist);
    conv_kernel<<<dim3(4096), dim3(256), 0, stream>>>(x, xbf, 1048576);
    convT_kernel<<<dim3(16, 16, NG), dim3(256), 0, stream>>>(blk_w, wbfT);
    wm_kernel<<<dim3(500, 16), dim3(256), 0, stream>>>(weight, gates_w, pos, wmbp);
    dbias_kernel<<<dim3(8160), dim3(256), 0, stream>>>(wmbp, blk_b, bias, jlist, pbase6, bias2);
    ceff_gemm<<<dim3(MAXTILES, 8), dim3(256), 0, stream>>>(wmbp, wbfT, jlist, tdesc, ceffv);
    out_gemm<<<dim3(250, 32), dim3(256), 0, stream>>>(xbf, ceffv, bias2, out);
}

// Round 10
// 989.954 us; speedup vs baseline: 1.5310x; 1.0417x over previous
//
#include <hip/hip_runtime.h>
#include <hip/hip_bf16.h>

#define VOCAB 32000
#define DIM 1024
#define NTOK 4096
#define NG 5
#define MAXTILES 255

typedef float f32x4 __attribute__((ext_vector_type(4)));
typedef __bf16 bf16x8 __attribute__((ext_vector_type(8)));

__device__ __forceinline__ unsigned short f2bf(float f) {
    union { float f; unsigned int u; } x; x.f = f;
    unsigned int r = x.u + 0x7fffu + ((x.u >> 16) & 1u);
    return (unsigned short)(r >> 16);
}
__device__ __forceinline__ float bf2f(unsigned short u) {
    union { unsigned int u; float f; } x; x.u = ((unsigned int)u) << 16;
    return x.f;
}

__device__ __forceinline__ void gload16(const void* g, void* l) {
    __builtin_amdgcn_global_load_lds(
        (const __attribute__((address_space(1))) void*)g,
        (__attribute__((address_space(3))) void*)l, 16, 0, 0);
}

// ---------------- scan stage 1: per-block selector histogram ----------------
__global__ __launch_bounds__(256) void hist_kernel(const float* __restrict__ gates_w,
                                                   int* __restrict__ hist) {
    __shared__ int cnt[NG];
    const int tid = threadIdx.x;
    if (tid < NG) cnt[tid] = 0;
    __syncthreads();
    const int v = blockIdx.x * 256 + tid;
    const int s = min(4, max(0, (int)floorf(gates_w[v] * 5.0f)));
    atomicAdd(&cnt[s], 1);
    __syncthreads();
    if (tid < NG) hist[blockIdx.x * NG + tid] = cnt[tid];
}

// ---------------- scan stage 2: bases, tile descriptors, jlist pads ---------
__global__ __launch_bounds__(64) void base_kernel(const int* __restrict__ hist,
                                                  int* __restrict__ blkoff,
                                                  int* __restrict__ jlist,
                                                  int4* __restrict__ tdesc,
                                                  int* __restrict__ pbase6) {
    __shared__ int histl[125 * NG];
    __shared__ int cnt[NG], pb[NG], padc[NG];
    const int tid = threadIdx.x;
    for (int i = tid; i < 125 * NG; i += 64) histl[i] = hist[i];
    __syncthreads();
    if (tid == 0) {
        int c[NG] = {0, 0, 0, 0, 0};
        for (int b = 0; b < 125; ++b)
            for (int g = 0; g < NG; ++g) c[g] += histl[b * NG + g];
        const int kmaxs[NG] = {256, 448, 640, 832, 1024};
        int p = 0, t = 0;
        for (int g = 0; g < NG; ++g) {
            pb[g] = p; cnt[g] = c[g];
            padc[g] = ((c[g] + 127) >> 7) << 7;
            pbase6[g] = p;
            p += padc[g];
        }
        pbase6[NG] = p;
        for (int g = 0; g < NG; ++g) {
            int nt = (cnt[g] + 127) >> 7;
            for (int k = 0; k < nt; ++k) { tdesc[t] = make_int4(g, pb[g] + (k << 7), kmaxs[g], 0); ++t; }
        }
        for (; t < MAXTILES; ++t) tdesc[t] = make_int4(-1, 0, 0, 0);
        int run[NG];
        for (int g = 0; g < NG; ++g) run[g] = pb[g];
        for (int b = 0; b < 125; ++b)
            for (int g = 0; g < NG; ++g) { blkoff[b * NG + g] = run[g]; run[g] += histl[b * NG + g]; }
    }
    __syncthreads();
    for (int g = 0; g < NG; ++g)
        for (int i = pb[g] + cnt[g] + tid; i < pb[g] + padc[g]; i += 64) jlist[i] = -1;
}

// ---------------- scan stage 3: stable positions ----------------------------
__global__ __launch_bounds__(256) void place_kernel(const float* __restrict__ gates_w,
                                                    const int* __restrict__ blkoff,
                                                    int* __restrict__ pos,
                                                    int* __restrict__ jlist) {
    __shared__ int wtot[4][NG], wpre[4][NG];
    const int tid = threadIdx.x, lane = tid & 63, wv = tid >> 6;
    const int v = blockIdx.x * 256 + tid;
    const int s = min(4, max(0, (int)floorf(gates_w[v] * 5.0f)));
    int rank = 0;
#pragma unroll
    for (int g = 0; g < NG; ++g) {
        unsigned long long m = __ballot(s == g);
        if (lane == 0) wtot[wv][g] = (int)__popcll(m);
        if (s == g) rank = (int)__popcll(m & ((1ull << lane) - 1ull));
    }
    __syncthreads();
    if (tid < NG) {
        int a = 0;
        for (int w = 0; w < 4; ++w) { wpre[w][tid] = a; a += wtot[w][tid]; }
    }
    __syncthreads();
    const int p = blkoff[blockIdx.x * NG + s] + wpre[wv][s] + rank;
    pos[v] = p;
    jlist[p] = v;
}

// ---------------- f32 -> bf16 convert (vectorized) --------------------------
__global__ void conv_kernel(const float* __restrict__ in, unsigned short* __restrict__ out, int n4) {
    int i = blockIdx.x * blockDim.x + threadIdx.x;
    if (i >= n4) return;
    const float4 f = ((const float4*)in)[i];
    ushort4 o;
    o.x = f2bf(f.x); o.y = f2bf(f.y); o.z = f2bf(f.z); o.w = f2bf(f.w);
    ((ushort4*)out)[i] = o;
}

// -------- blk_w [g][o][i] f32 -> wbfT [g][i][o] bf16 (transpose, f32x4 ld) --
__global__ __launch_bounds__(256) void convT_kernel(const float* __restrict__ blk_w,
                                                    unsigned short* __restrict__ wbfT) {
    __shared__ unsigned short tl[64][68];
    const int i0 = blockIdx.x * 64, o0 = blockIdx.y * 64, g = blockIdx.z;
    const int tid = threadIdx.x;
    const float* src = blk_w + (size_t)g * DIM * DIM;
    unsigned short* dst = wbfT + (size_t)g * DIM * DIM;
#pragma unroll
    for (int it = 0; it < 4; ++it) {
        int idx = it * 256 + tid;
        int lo = idx >> 4;
        int c4 = (idx & 15) * 4;
        float4 w = *(const float4*)&src[(size_t)(o0 + lo) * DIM + i0 + c4];
        tl[c4 + 0][lo] = f2bf(w.x);
        tl[c4 + 1][lo] = f2bf(w.y);
        tl[c4 + 2][lo] = f2bf(w.z);
        tl[c4 + 3][lo] = f2bf(w.w);
    }
    __syncthreads();
#pragma unroll
    for (int it = 0; it < 2; ++it) {
        int idx = it * 256 + tid;
        int ri = idx >> 3, ch = idx & 7;
        union { unsigned short u[8]; uint4 q; } uu;
#pragma unroll
        for (int k = 0; k < 8; ++k) uu.u[k] = tl[ri][ch * 8 + k];
        *(uint4*)(dst + (size_t)(i0 + ri) * DIM + o0 + ch * 8) = uu.q;
    }
}

// -------- masked weight: transpose [o][v] -> [pos[v]][o], bf16 (f32x4 ld) ---
__global__ __launch_bounds__(256) void wm_kernel(const float* __restrict__ weight,
                                                 const float* __restrict__ gates_w,
                                                 const int* __restrict__ pos,
                                                 unsigned short* __restrict__ wmbp) {
    __shared__ unsigned short tl[64][68];
    __shared__ float gatev[64];
    __shared__ int posv[64];
    const int v0 = blockIdx.x * 64, d0 = blockIdx.y * 64;
    const int tid = threadIdx.x;
    if (tid < 64) { gatev[tid] = gates_w[v0 + tid] * 1024.0f; posv[tid] = pos[v0 + tid]; }
    __syncthreads();
#pragma unroll
    for (int it = 0; it < 4; ++it) {
        int idx = it * 256 + tid;
        int ld = idx >> 4;
        int c4 = (idx & 15) * 4;
        const float dv = (float)(d0 + ld);
        float4 w = *(const float4*)&weight[(size_t)(d0 + ld) * VOCAB + v0 + c4];
        tl[c4 + 0][ld] = f2bf((dv < gatev[c4 + 0]) ? w.x : 0.0f);
        tl[c4 + 1][ld] = f2bf((dv < gatev[c4 + 1]) ? w.y : 0.0f);
        tl[c4 + 2][ld] = f2bf((dv < gatev[c4 + 2]) ? w.z : 0.0f);
        tl[c4 + 3][ld] = f2bf((dv < gatev[c4 + 3]) ? w.w : 0.0f);
    }
    __syncthreads();
#pragma unroll
    for (int it = 0; it < 2; ++it) {
        int idx = it * 256 + tid;
        int lv = idx >> 3, ch = idx & 7;
        union { unsigned short u[8]; uint4 q; } uu;
#pragma unroll
        for (int k = 0; k < 8; ++k) uu.u[k] = tl[lv][ch * 8 + k];
        *(uint4*)(wmbp + (size_t)posv[lv] * DIM + d0 + ch * 8) = uu.q;
    }
}

// ---------------- dbias: bias2[v] = bias[v] + dot(b_g, wmbp[p]) -------------
__global__ __launch_bounds__(256) void dbias_kernel(const unsigned short* __restrict__ wmbp,
                                                    const float* __restrict__ blk_b,
                                                    const float* __restrict__ bias,
                                                    const int* __restrict__ jlist,
                                                    const int* __restrict__ pbase6,
                                                    float* __restrict__ bias2) {
    const int p = blockIdx.x * 4 + (threadIdx.x >> 6);
    const int lane = threadIdx.x & 63;
    if (p >= pbase6[NG]) return;
    const int v = jlist[p];
    if (v < 0) return;
    int g = 0;
#pragma unroll
    for (int gg = 1; gg < NG; ++gg) if (p >= pbase6[gg]) g = gg;
    const unsigned short* wrow = wmbp + (size_t)p * DIM + lane * 16;
    const float* brow = blk_b + g * DIM + lane * 16;
    union { uint4 q; unsigned short u[8]; } a0, a1;
    a0.q = *(const uint4*)(wrow);
    a1.q = *(const uint4*)(wrow + 8);
    float s = 0.f;
#pragma unroll
    for (int k = 0; k < 8; ++k) s += bf2f(a0.u[k]) * brow[k];
#pragma unroll
    for (int k = 0; k < 8; ++k) s += bf2f(a1.u[k]) * brow[k + 8];
#pragma unroll
    for (int off = 32; off > 0; off >>= 1) s += __shfl_down(s, off);
    if (lane == 0) bias2[v] = bias[v] + s;
}

// ---------------- ceff GEMM: ceffv[v][i] = sum_o wmbp[p][o] * W_g[o][i] -----
__global__ __launch_bounds__(256, 2) void ceff_gemm(const unsigned short* __restrict__ wmbp,
                                                    const unsigned short* __restrict__ wbfT,
                                                    const int* __restrict__ jlist,
                                                    const int4* __restrict__ tdesc,
                                                    unsigned short* __restrict__ ceffv) {
    const int4 td = tdesc[blockIdx.x];
    if (td.x < 0) return;
    const int g = td.x, jb = td.y, kmax = td.z;
    const int n0 = blockIdx.y * 128;  // i-tile
    __shared__ __align__(16) unsigned short lA[128 * 64];
    __shared__ __align__(16) unsigned short lB[128 * 64];
    const int tid = threadIdx.x;
    const int lane = tid & 63, wv = tid >> 6;
    const int wm64 = (wv >> 1) * 64, wn64 = (wv & 1) * 64;
    const int lr = lane >> 4, lc = lane & 15;
    f32x4 acc[4][4] = {};
    const int r = tid >> 3, c = tid & 7;
    const unsigned short* sa = wmbp + (size_t)(jb + r) * DIM + c * 8;
    const unsigned short* sb = wbfT + (size_t)g * DIM * DIM + (size_t)(n0 + r) * DIM + c * 8;
    unsigned short* da = &lA[r * 64 + c * 8];
    unsigned short* db = &lB[r * 64 + c * 8];
    const int nkt = kmax >> 6;
    for (int kt = 0; kt < nkt; ++kt) {
#pragma unroll
        for (int s = 0; s < 4; ++s) {
            gload16(sa + (size_t)s * 32 * DIM + kt * 64, da + s * 32 * 64);
            gload16(sb + (size_t)s * 32 * DIM + kt * 64, db + s * 32 * 64);
        }
        __syncthreads();
#pragma unroll
        for (int kk = 0; kk < 64; kk += 32) {
            const int ko = kk + lr * 8;
            bf16x8 af[4], bg[4];
#pragma unroll
            for (int m = 0; m < 4; ++m) af[m] = *(const bf16x8*)&lA[(wm64 + m * 16 + lc) * 64 + ko];
#pragma unroll
            for (int n = 0; n < 4; ++n) bg[n] = *(const bf16x8*)&lB[(wn64 + n * 16 + lc) * 64 + ko];
#pragma unroll
            for (int m = 0; m < 4; ++m)
#pragma unroll
                for (int n = 0; n < 4; ++n)
                    acc[m][n] = __builtin_amdgcn_mfma_f32_16x16x32_bf16(af[m], bg[n], acc[m][n], 0, 0, 0);
        }
        __syncthreads();
    }
#pragma unroll
    for (int m = 0; m < 4; ++m) {
#pragma unroll
        for (int i = 0; i < 4; ++i) {
            const int prow = jb + wm64 + m * 16 + lr * 4 + i;
            const int v = jlist[prow];
            if (v < 0) continue;
#pragma unroll
            for (int n = 0; n < 4; ++n) {
                const int icol = n0 + wn64 + n * 16 + lc;
                ceffv[(size_t)v * DIM + icol] = f2bf(acc[m][n][i]);
            }
        }
    }
}

// ---------------- main dense GEMM: out = x . ceff^T + bias2 -----------------
// 256x256 tile, BK=64, 8 waves, 8-phase schedule with counted vmcnt (T3+T4+T5).
// K-split halves per K-tile: h0 = k 0..31, h1 = k 32..63 (16 KB each).
// Stage order per sub-iter t: q1:A1(t+1) q2:B1(t+1) q3:A0(t+2) q4:B0(t+2);
// vmcnt(4) at q4 -> every half lands >=1 barrier before first read (proof in notes).
#define BARRIER() do { asm volatile("" ::: "memory"); \
    __builtin_amdgcn_s_barrier(); asm volatile("" ::: "memory"); } while (0)
#define WAITV4() do { asm volatile("s_waitcnt vmcnt(4)" ::: "memory"); \
    __builtin_amdgcn_sched_barrier(0); } while (0)
#define WAITV0() do { asm volatile("s_waitcnt vmcnt(0)" ::: "memory"); \
    __builtin_amdgcn_sched_barrier(0); } while (0)

__global__ __launch_bounds__(512, 2) void out_gemm(const unsigned short* __restrict__ xbf,
                                                   const unsigned short* __restrict__ ceffv,
                                                   const float* __restrict__ bias2,
                                                   float* __restrict__ out) {
    // m-split XCD swizzle: 2000 blocks = 8 XCDs x (2 m-tiles x 125 n-tiles).
    // Each XCD owns 2 m-tiles (1 MB of A, L2-resident); n-fast, m inner pair.
    const int rid = blockIdx.x;
    const int c = rid & 7, l = rid >> 3;
    const int m0 = (c * 2 + (l & 1)) * 256;
    const int n0 = (l >> 1) * 256;
    __shared__ __align__(16) unsigned short lds[65536];  // 128 KiB
    const int tid = threadIdx.x;
    const int wv = tid >> 6, lane = tid & 63;
    const int wm = wv >> 2, wn = wv & 3;
    const int lc = lane & 15, lr = lane >> 4;
    f32x4 acc[8][4] = {};
    bf16x8 bg[4];

    // LDS slot bases (ushort offsets): A[b][h] = (b*2+h)*8192 ; B = 32768 + ...
    auto STAGE_A = [&](int t, int h, int b) {
#pragma unroll
        for (int j = 0; j < 2; ++j) {
            const int fi = j * 512 + tid;
            const int r = fi >> 2, kc8 = (fi & 3) * 8;
            gload16(xbf + (size_t)(m0 + r) * DIM + t * 64 + h * 32 + kc8,
                    &lds[(b * 2 + h) * 8192 + fi * 8]);
        }
    };
    auto STAGE_B = [&](int t, int h, int b) {
#pragma unroll
        for (int j = 0; j < 2; ++j) {
            const int fi = j * 512 + tid;
            const int r = fi >> 2, kc8 = (fi & 3) * 8;
            gload16(ceffv + (size_t)(n0 + r) * DIM + t * 64 + h * 32 + kc8,
                    &lds[32768 + (b * 2 + h) * 8192 + fi * 8]);
        }
    };

#define PHASE(mq, h, b, DO_B, STAGE_STMT, WAIT_STMT)                                   \
    {                                                                                   \
        const unsigned short* Ah = &lds[((b) * 2 + (h)) * 8192];                        \
        const unsigned short* Bh = &lds[32768 + ((b) * 2 + (h)) * 8192];                \
        bf16x8 af[4];                                                                   \
        _Pragma("unroll")                                                               \
        for (int mf = 0; mf < 4; ++mf)                                                  \
            af[mf] = *(const bf16x8*)&Ah[(wm * 128 + (mq) * 64 + mf * 16 + lc) * 32 + lr * 8]; \
        if (DO_B) {                                                                     \
            _Pragma("unroll")                                                           \
            for (int nf = 0; nf < 4; ++nf)                                              \
                bg[nf] = *(const bf16x8*)&Bh[(wn * 64 + nf * 16 + lc) * 32 + lr * 8];   \
        }                                                                               \
        STAGE_STMT;                                                                     \
        BARRIER();                                                                      \
        __builtin_amdgcn_s_setprio(1);                                                  \
        _Pragma("unroll")                                                               \
        for (int mf = 0; mf < 4; ++mf)                                                  \
            _Pragma("unroll")                                                           \
            for (int nf = 0; nf < 4; ++nf)                                              \
                acc[(mq) * 4 + mf][nf] = __builtin_amdgcn_mfma_f32_16x16x32_bf16(       \
                    af[mf], bg[nf], acc[(mq) * 4 + mf][nf], 0, 0, 0);                   \
        __builtin_amdgcn_s_setprio(0);                                                  \
        WAIT_STMT;                                                                      \
        BARRIER();                                                                      \
    }

    // prologue: K-tile0 all 4 halves + K-tile1 h0 halves, then full drain
    STAGE_A(0, 0, 0); STAGE_B(0, 0, 0);
    STAGE_A(0, 1, 0); STAGE_B(0, 1, 0);
    STAGE_A(1, 0, 1); STAGE_B(1, 0, 1);
    WAITV0();
    BARRIER();

    for (int t = 0; t < 14; ++t) {
        const int b = t & 1, nb = b ^ 1;
        PHASE(0, 0, b, true,  STAGE_A(t + 1, 1, nb), );
        PHASE(1, 0, b, false, STAGE_B(t + 1, 1, nb), );
        PHASE(0, 1, b, true,  STAGE_A(t + 2, 0, b), );
        PHASE(1, 1, b, false, STAGE_B(t + 2, 0, b), WAITV4());
    }
    // t = 14 (b=0): stages of t+2 don't exist; drain for the final tile's halves
    PHASE(0, 0, 0, true,  STAGE_A(15, 1, 1), );
    PHASE(1, 0, 0, false, STAGE_B(15, 1, 1), );
    PHASE(0, 1, 0, true,  , );
    PHASE(1, 1, 0, false, , WAITV0());
    // t = 15 (b=1): no stages
    PHASE(0, 0, 1, true,  , );
    PHASE(1, 0, 1, false, , );
    PHASE(0, 1, 1, true,  , );
    PHASE(1, 1, 1, false, , );

#undef PHASE

    // epilogue: nt f32 stores + bias
#pragma unroll
    for (int am = 0; am < 8; ++am) {
#pragma unroll
        for (int nf = 0; nf < 4; ++nf) {
            const int col = n0 + wn * 64 + nf * 16 + lc;
            const float b2 = bias2[col];
            const int t0 = m0 + wm * 128 + am * 16 + lr * 4;
#pragma unroll
            for (int i = 0; i < 4; ++i)
                __builtin_nontemporal_store(acc[am][nf][i] + b2,
                                            &out[(size_t)(t0 + i) * VOCAB + col]);
        }
    }
}

extern "C" void kernel_launch(void* const* d_in, const int* in_sizes, int n_in,
                              void* d_out, int out_size, void* d_ws, size_t ws_size,
                              hipStream_t stream) {
    const float* x       = (const float*)d_in[0];   // [2,2048,1024]
    const float* gates_w = (const float*)d_in[1];   // [32000,1]
    const float* weight  = (const float*)d_in[2];   // [1024,32000]
    const float* bias    = (const float*)d_in[3];   // [32000]
    const float* blk_w   = (const float*)d_in[4];   // [5,1024,1024]
    const float* blk_b   = (const float*)d_in[5];   // [5,1024]
    float* out = (float*)d_out;
    char* ws = (char*)d_ws;

    // workspace layout (bytes)
    unsigned short* xbf   = (unsigned short*)(ws);              //  8,388,608
    unsigned short* wbfT  = (unsigned short*)(ws + 8388608);    // 10,485,760
    unsigned short* wmbp  = (unsigned short*)(ws + 18874368);   // 66,846,720 (32640 x 1024)
    unsigned short* ceffv = (unsigned short*)(ws + 85721088);   // 65,536,000 (32000 x 1024)
    float* bias2 = (float*)(ws + 151257088);                    // 128,000
    int*   pos   = (int*)(ws + 151385088);                      // 128,000
    int*   jlist = (int*)(ws + 151513088);                      // 130,560
    int4*  tdesc = (int4*)(ws + 151643648);                     // 4,080
    int*   pbase6 = (int*)(ws + 151647728);                     // 24
    int*   hist   = (int*)(ws + 151647752);                     // 2,500
    int*   blkoff = (int*)(ws + 151650252);                     // 2,500

    hist_kernel<<<dim3(125), dim3(256), 0, stream>>>(gates_w, hist);
    base_kernel<<<dim3(1), dim3(64), 0, stream>>>(hist, blkoff, jlist, tdesc, pbase6);
    place_kernel<<<dim3(125), dim3(256), 0, stream>>>(gates_w, blkoff, pos, jlist);
    conv_kernel<<<dim3(4096), dim3(256), 0, stream>>>(x, xbf, 1048576);
    convT_kernel<<<dim3(16, 16, NG), dim3(256), 0, stream>>>(blk_w, wbfT);
    wm_kernel<<<dim3(500, 16), dim3(256), 0, stream>>>(weight, gates_w, pos, wmbp);
    dbias_kernel<<<dim3(8160), dim3(256), 0, stream>>>(wmbp, blk_b, bias, jlist, pbase6, bias2);
    ceff_gemm<<<dim3(MAXTILES, 8), dim3(256), 0, stream>>>(wmbp, wbfT, jlist, tdesc, ceffv);
    out_gemm<<<dim3(2000), dim3(512), 0, stream>>>(xbf, ceffv, bias2, out);
}